// Round 11
// baseline (94.306 us; speedup 1.0000x reference)
//
#include <hip/hip_runtime.h>
#include <hip/hip_bf16.h>
#include <stdint.h>

typedef _Float16 f16x8 __attribute__((ext_vector_type(8)));
typedef __fp16 hf2 __attribute__((ext_vector_type(2)));
typedef float f32x4 __attribute__((ext_vector_type(4)));
typedef unsigned int u32x4 __attribute__((ext_vector_type(4)));
typedef unsigned int u32x2 __attribute__((ext_vector_type(2)));

#define N_ATOMS 262144
#define NSYM 4
#define NIMG 1024

// ---------- kernel 1: per-block symbol counts ----------
__global__ void hist_kernel(const int* __restrict__ sym, int* __restrict__ wbh) {
  int b = blockIdx.x;
  int i = b * 256 + threadIdx.x;
  int lane = threadIdx.x & 63, wave = threadIdx.x >> 6;
  __shared__ int wcnt[4][NSYM];
  int s = sym[i];
#pragma unroll
  for (int t = 0; t < NSYM; ++t) {
    unsigned long long m = __ballot(s == t);
    if (lane == 0) wcnt[wave][t] = __popcll(m);
  }
  __syncthreads();
  if (threadIdx.x < NSYM)
    wbh[b * 4 + threadIdx.x] = wcnt[0][threadIdx.x] + wcnt[1][threadIdx.x] +
                               wcnt[2][threadIdx.x] + wcnt[3][threadIdx.x];
}

// ---------- kernel 2: scan -> offsets (256-padded), per-block bases, pad fill ----------
__global__ void offsets_kernel(const int* __restrict__ wbh, int* __restrict__ bases,
                               int* __restrict__ offs, int* __restrict__ perm) {
  __shared__ int wtot[4][NSYM];
  __shared__ int offsh[NSYM + 1];
  __shared__ int totsh[NSYM];
  int t = threadIdx.x, lane = t & 63, wave = t >> 6;
  int pre[4][NSYM];
  int sum[NSYM] = {0, 0, 0, 0};
#pragma unroll
  for (int k = 0; k < 4; ++k)
#pragma unroll
    for (int s2 = 0; s2 < NSYM; ++s2) {
      pre[k][s2] = sum[s2];
      sum[s2] += wbh[(t * 4 + k) * 4 + s2];
    }
  int inc[NSYM] = {sum[0], sum[1], sum[2], sum[3]};
  for (int d = 1; d < 64; d <<= 1) {
#pragma unroll
    for (int s2 = 0; s2 < NSYM; ++s2) {
      int v = __shfl_up(inc[s2], d);
      if (lane >= d) inc[s2] += v;
    }
  }
  if (lane == 63)
#pragma unroll
    for (int s2 = 0; s2 < NSYM; ++s2) wtot[wave][s2] = inc[s2];
  __syncthreads();
  int wb[NSYM];
#pragma unroll
  for (int s2 = 0; s2 < NSYM; ++s2) {
    wb[s2] = 0;
    for (int w = 0; w < wave; ++w) wb[s2] += wtot[w][s2];
  }
  if (t == 255)
#pragma unroll
    for (int s2 = 0; s2 < NSYM; ++s2) totsh[s2] = wb[s2] + inc[s2];
  __syncthreads();
  if (t == 0) {
    int o = 0;
    offsh[0] = 0; offs[0] = 0;
    for (int s2 = 0; s2 < NSYM; ++s2) {
      o += (totsh[s2] + 255) & ~255;
      offsh[s2 + 1] = o; offs[s2 + 1] = o;
    }
  }
  __syncthreads();
#pragma unroll
  for (int k = 0; k < 4; ++k)
#pragma unroll
    for (int s2 = 0; s2 < NSYM; ++s2)
      bases[(t * 4 + k) * 4 + s2] = offsh[s2] + wb[s2] + (inc[s2] - sum[s2]) + pre[k][s2];
  for (int s2 = 0; s2 < NSYM; ++s2) {
    int lo = offsh[s2] + totsh[s2], hi = offsh[s2 + 1];
    for (int i = lo + t; i < hi; i += 256) perm[i] = -1;
  }
}

// ---------- kernel 3: scatter + fused x->fp16 gather-convert ----------
// Phase 1: deterministic rank -> perm[off]=i, off kept in LDS.
// Phase 2 (do_cvt): read block's 256 x-rows COALESCED (1KB/instr), cvt fp16,
// write xg[off] rows (256B contiguous segments, scattered).
__global__ void scatter_kernel(const float* __restrict__ x, const int* __restrict__ sym,
                               const int* __restrict__ bases, int* __restrict__ perm,
                               unsigned short* __restrict__ xg, int do_cvt) {
  int b = blockIdx.x;
  int i = b * 256 + threadIdx.x;
  int lane = threadIdx.x & 63, wave = threadIdx.x >> 6;
  __shared__ int wcnt[4][NSYM];
  __shared__ int lds_off[256];
  int s = sym[i];
  unsigned long long mymask = 0;
#pragma unroll
  for (int t = 0; t < NSYM; ++t) {
    unsigned long long m = __ballot(s == t);
    if (lane == 0) wcnt[wave][t] = __popcll(m);
    if (s == t) mymask = m;
  }
  __syncthreads();
  int off = bases[b * 4 + s];
  for (int w = 0; w < wave; ++w) off += wcnt[w][s];
  off += __popcll(mymask & ((1ull << lane) - 1ull));
  perm[off] = i;
  lds_off[threadIdx.x] = off;
  if (!do_cvt) return;
  __syncthreads();

  // phase 2: wave w handles rows [w*64, w*64+64) of this block (2 rows/instr)
  int l32 = lane & 31, half = lane >> 5;
  int gbase = b * 256 + wave * 64;
#pragma unroll
  for (int it = 0; it < 4; ++it) {
    float4 v[8];
#pragma unroll
    for (int u = 0; u < 8; ++u) {
      int row = (it * 8 + u) * 2 + half;  // block-local within wave's 64
      v[u] = *(const float4*)(x + (size_t)(gbase + row) * 128 + l32 * 4);
    }
#pragma unroll
    for (int u = 0; u < 8; ++u) {
      int row = (it * 8 + u) * 2 + half;
      int o = lds_off[wave * 64 + row];
      hf2 p0 = __builtin_amdgcn_cvt_pkrtz(v[u].x, v[u].y);
      hf2 p1 = __builtin_amdgcn_cvt_pkrtz(v[u].z, v[u].w);
      u32x2 w2 = {__builtin_bit_cast(unsigned int, p0), __builtin_bit_cast(unsigned int, p1)};
      *(u32x2*)(xg + (size_t)o * 128 + l32 * 4) = w2;
    }
  }
}

// ---------- kernel 4: weights -> fp16 planes, PRE-SWIZZLED for global_load_lds ----------
__global__ void wconv_kernel(const float* __restrict__ W1, const float* __restrict__ W2,
                             unsigned short* __restrict__ wt) {
  int idx = blockIdx.x * 256 + threadIdx.x;  // 0..131071
  int t = idx >> 14;
  int layer = t >> 2, s = t & 3;
  int rem = idx & 16383;
  int h = rem >> 7, u = rem & 127;
  int gs = u >> 3, j = u & 7;
  int d = ((gs ^ (h & 7)) << 3) + j;
  const float* W = layer ? W2 : W1;
  _Float16 hv = (_Float16)W[(s * 128 + d) * 128 + h];  // RNE
  wt[t * 16384 + h * 128 + u] = __builtin_bit_cast(unsigned short, hv);
}

// ---------- kernel 5: fused 2-layer MLP, persistent ----------
// COAL=1: A-frags read directly from xg (fp16, perm order, 64B/atom dense) — no
// converts, no perm on the load path. COAL=0: round-10 gather fallback.
template <bool COAL>
__global__ __launch_bounds__(512, 2) void mlp_gemm(
    const float* __restrict__ x, const unsigned short* __restrict__ xg,
    const unsigned short* __restrict__ wt,
    const int* __restrict__ perm, const int* __restrict__ offs,
    const float* __restrict__ b1, const float* __restrict__ b2,
    const float* __restrict__ W3, const float* __restrict__ b3,
    const float* __restrict__ slope, const float* __restrict__ intercept,
    float* __restrict__ e_atom) {
  extern __shared__ char lds[];  // 128 KB

  int s = blockIdx.x >> 6;
  int kblk = blockIdx.x & 63;
  int base = offs[s];
  int T = (offs[s + 1] - base) >> 8;

  int tid = threadIdx.x;
  int wave = tid >> 6, lane = tid & 63;
  int r0 = lane & 15, chunk = lane >> 4;
  char* bounce = lds + 65536 + wave * 8192;

  const unsigned short* w1p = wt + (size_t)(0 + s) * 16384;
  const unsigned short* w2p = wt + (size_t)(4 + s) * 16384;

#pragma unroll
  for (int it = 0; it < 8; ++it) {
    int gb = it * 512 + wave * 64;
    const unsigned short* src = (gb >= 2048) ? (w2p + (size_t)(gb - 2048 + lane) * 8)
                                             : (w1p + (size_t)(gb + lane) * 8);
    __builtin_amdgcn_global_load_lds((const unsigned int*)src,
                                     (unsigned int*)(lds + (size_t)gb * 16), 16, 0, 0);
  }

  float b1v[8], b2v[8], w3v[8];
#pragma unroll
  for (int cf = 0; cf < 8; ++cf) {
    b1v[cf] = b1[s * 128 + cf * 16 + r0];
    b2v[cf] = b2[s * 128 + cf * 16 + r0];
    w3v[cf] = W3[s * 128 + cf * 16 + r0];
  }
  float sl = slope[s], ic = intercept[s], bb = b3[s];

  __syncthreads();  // W staged

  f32x4 zero4 = {0.f, 0.f, 0.f, 0.f};

  for (int t = kblk; t < T; t += 64) {
    f16x8 ah[8];
    if (COAL) {
      // ---- coalesced fp16 fragment loads from xg ----
#pragma unroll
      for (int rf = 0; rf < 2; ++rf) {
        const unsigned short* xr =
            xg + (size_t)(base + (t << 8) + wave * 32 + rf * 16 + r0) * 128;
#pragma unroll
        for (int kk = 0; kk < 4; ++kk)
          ah[rf * 4 + kk] = *(const f16x8*)(xr + kk * 32 + chunk * 8);
      }
    } else {
      // ---- round-10 fallback: perm gather + in-reg convert ----
      int a0 = perm[base + (t << 8) + wave * 32 + r0];
      int a1 = perm[base + (t << 8) + wave * 32 + 16 + r0];
#pragma unroll
      for (int rf = 0; rf < 2; ++rf) {
        int atom = rf ? a1 : a0;
        const float* xr = x + (long)(atom < 0 ? 0 : atom) * 128;
#pragma unroll
        for (int kk = 0; kk < 4; ++kk) {
          float4 v0 = *(const float4*)(xr + kk * 32 + chunk * 8);
          float4 v1 = *(const float4*)(xr + kk * 32 + chunk * 8 + 4);
          f16x8 f;
          f[0] = (_Float16)v0.x; f[1] = (_Float16)v0.y;
          f[2] = (_Float16)v0.z; f[3] = (_Float16)v0.w;
          f[4] = (_Float16)v1.x; f[5] = (_Float16)v1.y;
          f[6] = (_Float16)v1.z; f[7] = (_Float16)v1.w;
          ah[rf * 4 + kk] = f;
        }
      }
    }

    // ---- layer 1: acc = x * W1h, k-outer / cf-inner ----
    f32x4 acc[2][8];
#pragma unroll
    for (int i = 0; i < 2; ++i)
#pragma unroll
      for (int j = 0; j < 8; ++j) acc[i][j] = zero4;

#pragma unroll
    for (int k = 0; k < 4; ++k)
#pragma unroll
      for (int cf = 0; cf < 8; ++cf) {
        int row = cf * 16 + r0;
        f16x8 bh = *(const f16x8*)(lds + row * 256 +
                                   ((((k * 4 + chunk)) << 4) ^ ((row & 7) << 4)));
        acc[0][cf] = __builtin_amdgcn_mfma_f32_16x16x32_f16(ah[k], bh, acc[0][cf], 0, 0, 0);
        acc[1][cf] = __builtin_amdgcn_mfma_f32_16x16x32_f16(ah[4 + k], bh, acc[1][cf], 0, 0, 0);
      }

    // ---- bounce: h1 = relu(acc+b1) -> fp16, 2 half-passes ----
#pragma unroll
    for (int hp2 = 0; hp2 < 2; ++hp2) {
#pragma unroll
      for (int cf4 = 0; cf4 < 4; ++cf4) {
        int cf = hp2 * 4 + cf4;
        float bias = b1v[cf];
        int colp = cf4 * 16 + r0;
#pragma unroll
        for (int rf = 0; rf < 2; ++rf)
#pragma unroll
          for (int rr = 0; rr < 4; ++rr) {
            int row = rf * 16 + chunk * 4 + rr;
            float v = fmaxf(acc[rf][cf][rr] + bias, 0.f);
            unsigned short h = __builtin_bit_cast(unsigned short, (_Float16)v);  // RNE
            int cc = colp ^ (chunk << 4) ^ (rr << 2);
            *(unsigned int*)(bounce + row * 256 + cc * 4) = ((unsigned int)h << 16) | h;
          }
      }
#pragma unroll
      for (int kk2 = 0; kk2 < 2; ++kk2) {
        int kk = hp2 * 2 + kk2;
#pragma unroll
        for (int rf = 0; rf < 2; ++rf) {
          int row = rf * 16 + r0;
          int xr3 = ((r0 >> 2) << 4) ^ ((r0 & 3) << 2);
          int c0 = kk2 * 32 + chunk * 8;
          u32x4 pa = *(const u32x4*)(bounce + row * 256 + (c0 ^ xr3) * 4);
          u32x4 pb = *(const u32x4*)(bounce + row * 256 + ((c0 + 4) ^ xr3) * 4);
          unsigned int h01 = (pa[0] >> 16) | (pa[1] & 0xffff0000u);
          unsigned int h23 = (pa[2] >> 16) | (pa[3] & 0xffff0000u);
          unsigned int h45 = (pb[0] >> 16) | (pb[1] & 0xffff0000u);
          unsigned int h67 = (pb[2] >> 16) | (pb[3] & 0xffff0000u);
          u32x4 hq = {h01, h23, h45, h67};
          ah[rf * 4 + kk] = __builtin_bit_cast(f16x8, hq);
        }
      }
    }

    // ---- layer 2: acc = h1 * W2h ----
#pragma unroll
    for (int i = 0; i < 2; ++i)
#pragma unroll
      for (int j = 0; j < 8; ++j) acc[i][j] = zero4;

#pragma unroll
    for (int k = 0; k < 4; ++k)
#pragma unroll
      for (int cf = 0; cf < 8; ++cf) {
        int row = cf * 16 + r0;
        f16x8 bh = *(const f16x8*)(lds + 32768 + row * 256 +
                                   ((((k * 4 + chunk)) << 4) ^ ((row & 7) << 4)));
        acc[0][cf] = __builtin_amdgcn_mfma_f32_16x16x32_f16(ah[k], bh, acc[0][cf], 0, 0, 0);
        acc[1][cf] = __builtin_amdgcn_mfma_f32_16x16x32_f16(ah[4 + k], bh, acc[1][cf], 0, 0, 0);
      }

    // ---- epilogue: e = relu(acc+b2).W3, affine, scatter ----
    float p[2][4] = {{0.f, 0.f, 0.f, 0.f}, {0.f, 0.f, 0.f, 0.f}};
#pragma unroll
    for (int cf = 0; cf < 8; ++cf)
#pragma unroll
      for (int rf = 0; rf < 2; ++rf)
#pragma unroll
        for (int rr = 0; rr < 4; ++rr)
          p[rf][rr] += fmaxf(acc[rf][cf][rr] + b2v[cf], 0.f) * w3v[cf];
#pragma unroll
    for (int m = 1; m < 16; m <<= 1)
#pragma unroll
      for (int rf = 0; rf < 2; ++rf)
#pragma unroll
        for (int rr = 0; rr < 4; ++rr) p[rf][rr] += __shfl_xor(p[rf][rr], m);

    if (r0 == 0) {
#pragma unroll
      for (int rf = 0; rf < 2; ++rf)
#pragma unroll
        for (int rr = 0; rr < 4; ++rr) {
          int row = wave * 32 + rf * 16 + chunk * 4 + rr;
          int a = perm[base + (t << 8) + row];
          if (a >= 0) e_atom[a] = sl * (p[rf][rr] + bb) + ic;
        }
    }
  }
}

// ---------- kernel 6: deterministic per-image segment sum ----------
__global__ void segsum_kernel(const float* __restrict__ e_atom, const int* __restrict__ img,
                              float* __restrict__ out, int n) {
  int b = blockIdx.x;
  int lo = 0, hi = n;
  while (lo < hi) { int m = (lo + hi) >> 1; if (img[m] < b) lo = m + 1; else hi = m; }
  int lo2 = lo, hi2 = n;
  while (lo2 < hi2) { int m = (lo2 + hi2) >> 1; if (img[m] < b + 1) lo2 = m + 1; else hi2 = m; }
  float sum = 0.f;
  for (int i = lo + threadIdx.x; i < lo2; i += blockDim.x) sum += e_atom[i];
  for (int m = 32; m; m >>= 1) sum += __shfl_down(sum, m);
  __shared__ float part[4];
  int lane = threadIdx.x & 63, wave = threadIdx.x >> 6;
  if (lane == 0) part[wave] = sum;
  __syncthreads();
  if (threadIdx.x == 0) out[b] = part[0] + part[1] + part[2] + part[3];
}

extern "C" void kernel_launch(void* const* d_in, const int* in_sizes, int n_in,
                              void* d_out, int out_size, void* d_ws, size_t ws_size,
                              hipStream_t stream) {
  const float* x         = (const float*)d_in[0];
  const float* W1        = (const float*)d_in[1];
  const float* b1        = (const float*)d_in[2];
  const float* W2        = (const float*)d_in[3];
  const float* b2        = (const float*)d_in[4];
  const float* W3        = (const float*)d_in[5];
  const float* b3        = (const float*)d_in[6];
  const float* slope     = (const float*)d_in[7];
  const float* intercept = (const float*)d_in[8];
  const int* sym         = (const int*)d_in[9];
  const int* img         = (const int*)d_in[10];

  char* ws = (char*)d_ws;
  int* wbh    = (int*)ws;                          // 16384 B
  int* bases  = (int*)(ws + 16384);                // 16384 B
  int* offs   = (int*)(ws + 32768);                // 64 B
  int* perm   = (int*)(ws + 32832);                // (N+1024)*4 = 1052672 B
  float* e_atom = (float*)(ws + 32832 + 1052672);  // N*4 = 1048576 B
  unsigned short* wt = (unsigned short*)(ws + 2134080);  // 256 KB -> ends 2396224
  size_t xg_off = 2396416;  // 256-aligned
  size_t xg_bytes = (size_t)(N_ATOMS + 1024) * 256;
  unsigned short* xg = (unsigned short*)(ws + xg_off);
  int coal = (ws_size >= xg_off + xg_bytes) ? 1 : 0;

  hist_kernel<<<1024, 256, 0, stream>>>(sym, wbh);
  offsets_kernel<<<1, 256, 0, stream>>>(wbh, bases, offs, perm);
  scatter_kernel<<<1024, 256, 0, stream>>>(x, sym, bases, perm, xg, coal);
  wconv_kernel<<<512, 256, 0, stream>>>(W1, W2, wt);
  if (coal)
    mlp_gemm<true><<<256, 512, 131072, stream>>>(x, xg, wt, perm, offs, b1, b2,
                                                 W3, b3, slope, intercept, e_atom);
  else
    mlp_gemm<false><<<256, 512, 131072, stream>>>(x, xg, wt, perm, offs, b1, b2,
                                                  W3, b3, slope, intercept, e_atom);
  segsum_kernel<<<NIMG, 256, 0, stream>>>(e_atom, img, (float*)d_out, N_ATOMS);
}

// Round 12
// 64.894 us; speedup vs baseline: 1.4532x; 1.4532x over previous
//
#include <hip/hip_runtime.h>
#include <hip/hip_bf16.h>
#include <stdint.h>

typedef _Float16 f16x8 __attribute__((ext_vector_type(8)));
typedef __fp16 hf2 __attribute__((ext_vector_type(2)));
typedef float f32x4 __attribute__((ext_vector_type(4)));
typedef unsigned int u32x4 __attribute__((ext_vector_type(4)));
typedef unsigned int u32x2 __attribute__((ext_vector_type(2)));

#define N_ATOMS 262144
#define NSYM 4
#define NIMG 1024

// ---------- kernel 1: per-block symbol counts ----------
__global__ void hist_kernel(const int* __restrict__ sym, int* __restrict__ wbh) {
  int b = blockIdx.x;
  int i = b * 256 + threadIdx.x;
  int lane = threadIdx.x & 63, wave = threadIdx.x >> 6;
  __shared__ int wcnt[4][NSYM];
  int s = sym[i];
#pragma unroll
  for (int t = 0; t < NSYM; ++t) {
    unsigned long long m = __ballot(s == t);
    if (lane == 0) wcnt[wave][t] = __popcll(m);
  }
  __syncthreads();
  if (threadIdx.x < NSYM)
    wbh[b * 4 + threadIdx.x] = wcnt[0][threadIdx.x] + wcnt[1][threadIdx.x] +
                               wcnt[2][threadIdx.x] + wcnt[3][threadIdx.x];
}

// ---------- kernel 2: scan -> offsets (256-padded), per-block bases, pad fill ----------
__global__ void offsets_kernel(const int* __restrict__ wbh, int* __restrict__ bases,
                               int* __restrict__ offs, int* __restrict__ perm) {
  __shared__ int wtot[4][NSYM];
  __shared__ int offsh[NSYM + 1];
  __shared__ int totsh[NSYM];
  int t = threadIdx.x, lane = t & 63, wave = t >> 6;
  int pre[4][NSYM];
  int sum[NSYM] = {0, 0, 0, 0};
#pragma unroll
  for (int k = 0; k < 4; ++k)
#pragma unroll
    for (int s2 = 0; s2 < NSYM; ++s2) {
      pre[k][s2] = sum[s2];
      sum[s2] += wbh[(t * 4 + k) * 4 + s2];
    }
  int inc[NSYM] = {sum[0], sum[1], sum[2], sum[3]};
  for (int d = 1; d < 64; d <<= 1) {
#pragma unroll
    for (int s2 = 0; s2 < NSYM; ++s2) {
      int v = __shfl_up(inc[s2], d);
      if (lane >= d) inc[s2] += v;
    }
  }
  if (lane == 63)
#pragma unroll
    for (int s2 = 0; s2 < NSYM; ++s2) wtot[wave][s2] = inc[s2];
  __syncthreads();
  int wb[NSYM];
#pragma unroll
  for (int s2 = 0; s2 < NSYM; ++s2) {
    wb[s2] = 0;
    for (int w = 0; w < wave; ++w) wb[s2] += wtot[w][s2];
  }
  if (t == 255)
#pragma unroll
    for (int s2 = 0; s2 < NSYM; ++s2) totsh[s2] = wb[s2] + inc[s2];
  __syncthreads();
  if (t == 0) {
    int o = 0;
    offsh[0] = 0; offs[0] = 0;
    for (int s2 = 0; s2 < NSYM; ++s2) {
      o += (totsh[s2] + 255) & ~255;
      offsh[s2 + 1] = o; offs[s2 + 1] = o;
    }
  }
  __syncthreads();
#pragma unroll
  for (int k = 0; k < 4; ++k)
#pragma unroll
    for (int s2 = 0; s2 < NSYM; ++s2)
      bases[(t * 4 + k) * 4 + s2] = offsh[s2] + wb[s2] + (inc[s2] - sum[s2]) + pre[k][s2];
  for (int s2 = 0; s2 < NSYM; ++s2) {
    int lo = offsh[s2] + totsh[s2], hi = offsh[s2 + 1];
    for (int i = lo + t; i < hi; i += 256) perm[i] = -1;
  }
}

// ---------- kernel 3: deterministic scatter (perm only) ----------
__global__ void scatter_kernel(const int* __restrict__ sym, const int* __restrict__ bases,
                               int* __restrict__ perm) {
  int b = blockIdx.x;
  int i = b * 256 + threadIdx.x;
  int lane = threadIdx.x & 63, wave = threadIdx.x >> 6;
  __shared__ int wcnt[4][NSYM];
  int s = sym[i];
  unsigned long long mymask = 0;
#pragma unroll
  for (int t = 0; t < NSYM; ++t) {
    unsigned long long m = __ballot(s == t);
    if (lane == 0) wcnt[wave][t] = __popcll(m);
    if (s == t) mymask = m;
  }
  __syncthreads();
  int off = bases[b * 4 + s];
  for (int w = 0; w < wave; ++w) off += wcnt[w][s];
  off += __popcll(mymask & ((1ull << lane) - 1ull));
  perm[off] = i;
}

// ---------- kernel 4: weights -> fp16 planes, PRE-SWIZZLED for global_load_lds ----------
__global__ void wconv_kernel(const float* __restrict__ W1, const float* __restrict__ W2,
                             unsigned short* __restrict__ wt) {
  int idx = blockIdx.x * 256 + threadIdx.x;  // 0..131071
  int t = idx >> 14;
  int layer = t >> 2, s = t & 3;
  int rem = idx & 16383;
  int h = rem >> 7, u = rem & 127;
  int gs = u >> 3, j = u & 7;
  int d = ((gs ^ (h & 7)) << 3) + j;
  const float* W = layer ? W2 : W1;
  _Float16 hv = (_Float16)W[(s * 128 + d) * 128 + h];  // RNE
  wt[t * 16384 + h * 128 + u] = __builtin_bit_cast(unsigned short, hv);
}

// ---------- kernel 5: fused 2-layer MLP, persistent, dense-row LDS-staged gather ----------
// 256 blocks x 8 waves x 32 atoms. LDS 128KB: W1h[0,32K) W2h[32K,64K) once;
// stage/bounce 8KB/wave at [64K+). Per tile: x rows loaded as FULL 512B dense
// segments (2 rows/instr), cvt fp16, LDS-transposed to A-frags; T14 prefetch of
// next tile's rows under layer2+epilogue. perm via one lane-load + shfl.
__global__ __launch_bounds__(512, 2) void mlp_gemm(
    const float* __restrict__ x, const unsigned short* __restrict__ wt,
    const int* __restrict__ perm, const int* __restrict__ offs,
    const float* __restrict__ b1, const float* __restrict__ b2,
    const float* __restrict__ W3, const float* __restrict__ b3,
    const float* __restrict__ slope, const float* __restrict__ intercept,
    float* __restrict__ e_atom) {
  extern __shared__ char lds[];  // 128 KB

  int s = blockIdx.x >> 6;
  int kblk = blockIdx.x & 63;
  int base = offs[s];
  int T = (offs[s + 1] - base) >> 8;

  int tid = threadIdx.x;
  int wave = tid >> 6, lane = tid & 63;
  int r0 = lane & 15, chunk = lane >> 4;
  int l32 = lane & 31, half = lane >> 5;
  char* stage = lds + 65536 + wave * 8192;  // x-stage, then h1-bounce

  const unsigned short* w1p = wt + (size_t)(0 + s) * 16384;
  const unsigned short* w2p = wt + (size_t)(4 + s) * 16384;

  // ---- stage W1h+W2h once (async DMA, pre-swizzled source, linear dest) ----
#pragma unroll
  for (int it = 0; it < 8; ++it) {
    int gb = it * 512 + wave * 64;
    const unsigned short* src = (gb >= 2048) ? (w2p + (size_t)(gb - 2048 + lane) * 8)
                                             : (w1p + (size_t)(gb + lane) * 8);
    __builtin_amdgcn_global_load_lds((const unsigned int*)src,
                                     (unsigned int*)(lds + (size_t)gb * 16), 16, 0, 0);
  }

  float b1v[8], b2v[8], w3v[8];
#pragma unroll
  for (int cf = 0; cf < 8; ++cf) {
    b1v[cf] = b1[s * 128 + cf * 16 + r0];
    b2v[cf] = b2[s * 128 + cf * 16 + r0];
    w3v[cf] = W3[s * 128 + cf * 16 + r0];
  }
  float sl = slope[s], ic = intercept[s], bb = b3[s];

  // ---- prologue: tile kblk's perm + dense row loads (overlap W DMA) ----
  int cur_perm = (kblk < T) ? perm[base + (kblk << 8) + wave * 32 + l32] : -1;
  float4 raw[16];
#pragma unroll
  for (int it = 0; it < 16; ++it) {
    int atom = __shfl(cur_perm, it * 2 + half);
    raw[it] = *(const float4*)(x + (size_t)(atom < 0 ? 0 : atom) * 128 + l32 * 4);
  }

  __syncthreads();  // W staged

  f32x4 zero4 = {0.f, 0.f, 0.f, 0.f};

  for (int t = kblk; t < T; t += 64) {
    int tn = t + 64;
    int nperm = -1;
    if (tn < T) nperm = perm[base + (tn << 8) + wave * 32 + l32];

    // ---- stage-write: cvt fp16 + swizzled ds_write (2 dense rows/instr src) ----
#pragma unroll
    for (int it = 0; it < 16; ++it) {
      int row = it * 2 + half;
      hf2 p0 = __builtin_amdgcn_cvt_pkrtz(raw[it].x, raw[it].y);
      hf2 p1 = __builtin_amdgcn_cvt_pkrtz(raw[it].z, raw[it].w);
      u32x2 w2 = {__builtin_bit_cast(unsigned int, p0), __builtin_bit_cast(unsigned int, p1)};
      int gs = (l32 >> 1) ^ (row & 7);
      *(u32x2*)(stage + row * 256 + gs * 16 + (l32 & 1) * 8) = w2;
    }
    // ---- stage-read: A fragments (conflict-free b128) ----
    f16x8 ah[8];
#pragma unroll
    for (int rf = 0; rf < 2; ++rf)
#pragma unroll
      for (int kk = 0; kk < 4; ++kk) {
        int row = rf * 16 + r0;
        ah[rf * 4 + kk] = *(const f16x8*)(stage + row * 256 +
                                          (((kk * 4 + chunk) ^ (row & 7)) << 4));
      }

    // ---- layer 1: acc = x * W1h, k-outer / cf-inner ----
    f32x4 acc[2][8];
#pragma unroll
    for (int i = 0; i < 2; ++i)
#pragma unroll
      for (int j = 0; j < 8; ++j) acc[i][j] = zero4;

#pragma unroll
    for (int k = 0; k < 4; ++k)
#pragma unroll
      for (int cf = 0; cf < 8; ++cf) {
        int row = cf * 16 + r0;
        f16x8 bh = *(const f16x8*)(lds + row * 256 +
                                   ((((k * 4 + chunk)) << 4) ^ ((row & 7) << 4)));
        acc[0][cf] = __builtin_amdgcn_mfma_f32_16x16x32_f16(ah[k], bh, acc[0][cf], 0, 0, 0);
        acc[1][cf] = __builtin_amdgcn_mfma_f32_16x16x32_f16(ah[4 + k], bh, acc[1][cf], 0, 0, 0);
      }

    // ---- bounce: h1 = relu(acc+b1) -> fp16, 2 half-passes (reuses stage) ----
#pragma unroll
    for (int hp2 = 0; hp2 < 2; ++hp2) {
#pragma unroll
      for (int cf4 = 0; cf4 < 4; ++cf4) {
        int cf = hp2 * 4 + cf4;
        float bias = b1v[cf];
        int colp = cf4 * 16 + r0;
#pragma unroll
        for (int rf = 0; rf < 2; ++rf)
#pragma unroll
          for (int rr = 0; rr < 4; ++rr) {
            int row = rf * 16 + chunk * 4 + rr;
            float v = fmaxf(acc[rf][cf][rr] + bias, 0.f);
            unsigned short h = __builtin_bit_cast(unsigned short, (_Float16)v);  // RNE
            int cc = colp ^ (chunk << 4) ^ (rr << 2);
            *(unsigned int*)(stage + row * 256 + cc * 4) = ((unsigned int)h << 16) | h;
          }
      }
#pragma unroll
      for (int kk2 = 0; kk2 < 2; ++kk2) {
        int kk = hp2 * 2 + kk2;
#pragma unroll
        for (int rf = 0; rf < 2; ++rf) {
          int row = rf * 16 + r0;
          int xr3 = ((r0 >> 2) << 4) ^ ((r0 & 3) << 2);
          int c0 = kk2 * 32 + chunk * 8;
          u32x4 pa = *(const u32x4*)(stage + row * 256 + (c0 ^ xr3) * 4);
          u32x4 pb = *(const u32x4*)(stage + row * 256 + ((c0 + 4) ^ xr3) * 4);
          unsigned int h01 = (pa[0] >> 16) | (pa[1] & 0xffff0000u);
          unsigned int h23 = (pa[2] >> 16) | (pa[3] & 0xffff0000u);
          unsigned int h45 = (pb[0] >> 16) | (pb[1] & 0xffff0000u);
          unsigned int h67 = (pb[2] >> 16) | (pb[3] & 0xffff0000u);
          u32x4 hq = {h01, h23, h45, h67};
          ah[rf * 4 + kk] = __builtin_bit_cast(f16x8, hq);
        }
      }
    }

    // ---- T14: issue next tile's dense row loads (land under layer2+epilogue) ----
    if (tn < T) {
#pragma unroll
      for (int it = 0; it < 16; ++it) {
        int atom = __shfl(nperm, it * 2 + half);
        raw[it] = *(const float4*)(x + (size_t)(atom < 0 ? 0 : atom) * 128 + l32 * 4);
      }
    }

    // ---- layer 2: acc = h1 * W2h ----
#pragma unroll
    for (int i = 0; i < 2; ++i)
#pragma unroll
      for (int j = 0; j < 8; ++j) acc[i][j] = zero4;

#pragma unroll
    for (int k = 0; k < 4; ++k)
#pragma unroll
      for (int cf = 0; cf < 8; ++cf) {
        int row = cf * 16 + r0;
        f16x8 bh = *(const f16x8*)(lds + 32768 + row * 256 +
                                   ((((k * 4 + chunk)) << 4) ^ ((row & 7) << 4)));
        acc[0][cf] = __builtin_amdgcn_mfma_f32_16x16x32_f16(ah[k], bh, acc[0][cf], 0, 0, 0);
        acc[1][cf] = __builtin_amdgcn_mfma_f32_16x16x32_f16(ah[4 + k], bh, acc[1][cf], 0, 0, 0);
      }

    // ---- epilogue: e = relu(acc+b2).W3, affine, scatter ----
    float p[2][4] = {{0.f, 0.f, 0.f, 0.f}, {0.f, 0.f, 0.f, 0.f}};
#pragma unroll
    for (int cf = 0; cf < 8; ++cf)
#pragma unroll
      for (int rf = 0; rf < 2; ++rf)
#pragma unroll
        for (int rr = 0; rr < 4; ++rr)
          p[rf][rr] += fmaxf(acc[rf][cf][rr] + b2v[cf], 0.f) * w3v[cf];
#pragma unroll
    for (int m = 1; m < 16; m <<= 1)
#pragma unroll
      for (int rf = 0; rf < 2; ++rf)
#pragma unroll
        for (int rr = 0; rr < 4; ++rr) p[rf][rr] += __shfl_xor(p[rf][rr], m);

    int atom_w[2][4];
#pragma unroll
    for (int rf = 0; rf < 2; ++rf)
#pragma unroll
      for (int rr = 0; rr < 4; ++rr)
        atom_w[rf][rr] = __shfl(cur_perm, rf * 16 + chunk * 4 + rr);

    if (r0 == 0) {
#pragma unroll
      for (int rf = 0; rf < 2; ++rf)
#pragma unroll
        for (int rr = 0; rr < 4; ++rr)
          if (atom_w[rf][rr] >= 0)
            e_atom[atom_w[rf][rr]] = sl * (p[rf][rr] + bb) + ic;
    }

    cur_perm = nperm;
  }
}

// ---------- kernel 6: deterministic per-image segment sum ----------
__global__ void segsum_kernel(const float* __restrict__ e_atom, const int* __restrict__ img,
                              float* __restrict__ out, int n) {
  int b = blockIdx.x;
  int lo = 0, hi = n;
  while (lo < hi) { int m = (lo + hi) >> 1; if (img[m] < b) lo = m + 1; else hi = m; }
  int lo2 = lo, hi2 = n;
  while (lo2 < hi2) { int m = (lo2 + hi2) >> 1; if (img[m] < b + 1) lo2 = m + 1; else hi2 = m; }
  float sum = 0.f;
  for (int i = lo + threadIdx.x; i < lo2; i += blockDim.x) sum += e_atom[i];
  for (int m = 32; m; m >>= 1) sum += __shfl_down(sum, m);
  __shared__ float part[4];
  int lane = threadIdx.x & 63, wave = threadIdx.x >> 6;
  if (lane == 0) part[wave] = sum;
  __syncthreads();
  if (threadIdx.x == 0) out[b] = part[0] + part[1] + part[2] + part[3];
}

extern "C" void kernel_launch(void* const* d_in, const int* in_sizes, int n_in,
                              void* d_out, int out_size, void* d_ws, size_t ws_size,
                              hipStream_t stream) {
  const float* x         = (const float*)d_in[0];
  const float* W1        = (const float*)d_in[1];
  const float* b1        = (const float*)d_in[2];
  const float* W2        = (const float*)d_in[3];
  const float* b2        = (const float*)d_in[4];
  const float* W3        = (const float*)d_in[5];
  const float* b3        = (const float*)d_in[6];
  const float* slope     = (const float*)d_in[7];
  const float* intercept = (const float*)d_in[8];
  const int* sym         = (const int*)d_in[9];
  const int* img         = (const int*)d_in[10];

  char* ws = (char*)d_ws;
  int* wbh    = (int*)ws;                          // 16384 B
  int* bases  = (int*)(ws + 16384);                // 16384 B
  int* offs   = (int*)(ws + 32768);                // 64 B
  int* perm   = (int*)(ws + 32832);                // (N+1024)*4
  float* e_atom = (float*)(ws + 32832 + 1052672);  // N*4
  unsigned short* wt = (unsigned short*)(ws + 2134080);  // 256 KB

  hist_kernel<<<1024, 256, 0, stream>>>(sym, wbh);
  offsets_kernel<<<1, 256, 0, stream>>>(wbh, bases, offs, perm);
  scatter_kernel<<<1024, 256, 0, stream>>>(sym, bases, perm);
  wconv_kernel<<<512, 256, 0, stream>>>(W1, W2, wt);
  mlp_gemm<<<256, 512, 131072, stream>>>(x, wt, perm, offs, b1, b2,
                                         W3, b3, slope, intercept, e_atom);
  segsum_kernel<<<NIMG, 256, 0, stream>>>(e_atom, img, (float*)d_out, N_ATOMS);
}